// Round 1
// baseline (112.062 us; speedup 1.0000x reference)
//
#include <hip/hip_runtime.h>

#define NS   256          // batch rows
#define FEAT 8192
#define BD   128
#define CD   16
#define NOUT 2048         // BD*CD
#define OUTW (FEAT + BD)  // 8320

typedef float f32x4 __attribute__((ext_vector_type(4)));
typedef short bf16x8 __attribute__((ext_vector_type(8)));
typedef short bf16x4 __attribute__((ext_vector_type(4)));

__device__ __forceinline__ short f32_bf16(float f) {
    union { float f; unsigned u; } v; v.f = f;
    unsigned r = v.u + 0x7FFFu + ((v.u >> 16) & 1u);   // round-to-nearest-even
    return (short)(r >> 16);
}

// ---------------------------------------------------------------- copy inp ->
__global__ __launch_bounds__(256) void mbd_copy_kernel(const float* __restrict__ in,
                                                       float* __restrict__ out) {
    int idx = blockIdx.x * 256 + threadIdx.x;      // one float4 per thread
    int row = idx >> 11;                           // 2048 float4-chunks per row
    int c4  = idx & 2047;
    *(f32x4*)(out + (size_t)row * OUTW + c4 * 4) =
        *(const f32x4*)(in + (size_t)row * FEAT + c4 * 4);
}

// ---------------------------------------------------------------- GEMM ------
// M[256][2048] += inp[256][8192] @ T[8192][2048], bf16 MFMA, 8-way K-split.
#define BK     32
#define LDA_P  40    // A LDS row pitch in bf16 (80 B: b128-aligned, 2-way-free)
#define LDB_P  132   // B LDS row pitch in bf16 (264 B: b64-aligned writes)
#define KCHUNK 1024

__global__ __launch_bounds__(256) void mbd_gemm_kernel(const float* __restrict__ A,
                                                       const float* __restrict__ B,
                                                       float* __restrict__ C) {
    __shared__ short Als[128 * LDA_P];
    __shared__ short Bls[BK * LDB_P];

    const int tid  = threadIdx.x;
    const int lane = tid & 63;
    const int w    = tid >> 6;
    const int wr   = (w >> 1) * 64;   // wave's 64x64 sub-tile
    const int wc   = (w & 1) * 64;

    const int bx = blockIdx.x;
    const int kc = bx & 7;            // K-chunk 0..7
    const int t  = bx >> 3;
    const int m0 = (t & 1) * 128;     // 2 M-tiles
    const int n0 = (t >> 1) * 128;    // 16 N-tiles

    f32x4 acc[4][4];
#pragma unroll
    for (int m = 0; m < 4; ++m)
#pragma unroll
        for (int n = 0; n < 4; ++n)
            acc[m][n] = (f32x4){0.f, 0.f, 0.f, 0.f};

    const int l15 = lane & 15;
    const int kof = (lane >> 4) * 8;  // k-offset of this lane's fragment slice

    for (int kt = 0; kt < KCHUNK / BK; ++kt) {
        const int k0 = kc * KCHUNK + kt * BK;

        // stage A-tile 128x32 f32 -> bf16 LDS
#pragma unroll
        for (int i = 0; i < 4; ++i) {
            int id  = tid + i * 256;
            int row = id >> 3, kk = (id & 7) * 4;
            f32x4 v = *(const f32x4*)(A + (size_t)(m0 + row) * FEAT + k0 + kk);
            bf16x4 s;
            s.x = f32_bf16(v.x); s.y = f32_bf16(v.y);
            s.z = f32_bf16(v.z); s.w = f32_bf16(v.w);
            *(bf16x4*)&Als[row * LDA_P + kk] = s;
        }
        // stage B-tile 32x128 f32 -> bf16 LDS (row-major)
#pragma unroll
        for (int i = 0; i < 4; ++i) {
            int id = tid + i * 256;
            int kr = id >> 5, nn = (id & 31) * 4;
            f32x4 v = *(const f32x4*)(B + (size_t)(k0 + kr) * NOUT + n0 + nn);
            bf16x4 s;
            s.x = f32_bf16(v.x); s.y = f32_bf16(v.y);
            s.z = f32_bf16(v.z); s.w = f32_bf16(v.w);
            *(bf16x4*)&Bls[kr * LDB_P + nn] = s;
        }
        __syncthreads();

        // A fragments: row = l&15, k = (l>>4)*8 + e (contiguous b128 read)
        bf16x8 af[4], bf[4];
#pragma unroll
        for (int m = 0; m < 4; ++m) {
            int row = wr + m * 16 + l15;
            af[m] = *(const bf16x8*)&Als[row * LDA_P + kof];
        }
        // B fragments: col = l&15, k = (l>>4)*8 + e (scalar u16 reads, R0 known-slow)
#pragma unroll
        for (int n = 0; n < 4; ++n) {
            int col = wc + n * 16 + l15;
            bf16x8 tmp;
#pragma unroll
            for (int e = 0; e < 8; ++e) tmp[e] = Bls[(kof + e) * LDB_P + col];
            bf[n] = tmp;
        }
        __syncthreads();

#pragma unroll
        for (int m = 0; m < 4; ++m)
#pragma unroll
            for (int n = 0; n < 4; ++n)
                acc[m][n] = __builtin_amdgcn_mfma_f32_16x16x32_bf16(
                    af[m], bf[n], acc[m][n], 0, 0, 0);
    }

    // epilogue: C/D layout col = l&15, row = (l>>4)*4 + r  [m89-verified]
    const int r0 = (lane >> 4) * 4;
#pragma unroll
    for (int m = 0; m < 4; ++m) {
#pragma unroll
        for (int n = 0; n < 4; ++n) {
            int col = n0 + wc + n * 16 + l15;
#pragma unroll
            for (int r = 0; r < 4; ++r) {
                int row = m0 + wr + m * 16 + r0 + r;
                atomicAdd(&C[(size_t)row * NOUT + col], acc[m][n][r]);
            }
        }
    }
}

// ---------------------------------------------------------------- pairwise --
// o[i,b] = sum_j exp(-sum_c |M[i,b,c]-M[j,b,c]|); one block per b.
__global__ __launch_bounds__(256) void mbd_pair_kernel(const float* __restrict__ M,
                                                       float* __restrict__ out) {
    const int b = blockIdx.x;
    const int i = threadIdx.x;
    __shared__ float rows[NS][CD];   // 16 KB

    f32x4 my[4];
    const float* mp = M + (size_t)i * NOUT + b * CD;
#pragma unroll
    for (int q = 0; q < 4; ++q) my[q] = *(const f32x4*)(mp + q * 4);
#pragma unroll
    for (int q = 0; q < 4; ++q) *(f32x4*)&rows[i][q * 4] = my[q];
    __syncthreads();

    float o = 0.f;
    for (int j = 0; j < NS; ++j) {
        const f32x4* rp = (const f32x4*)&rows[j][0];   // uniform j -> broadcast
        float d = 0.f;
#pragma unroll
        for (int q = 0; q < 4; ++q) {
            f32x4 r = rp[q];
            d += fabsf(my[q].x - r.x) + fabsf(my[q].y - r.y) +
                 fabsf(my[q].z - r.z) + fabsf(my[q].w - r.w);
        }
        o += __expf(-d);
    }
    out[(size_t)i * OUTW + FEAT + b] = o;
}

// ---------------------------------------------------------------- launch ----
extern "C" void kernel_launch(void* const* d_in, const int* in_sizes, int n_in,
                              void* d_out, int out_size, void* d_ws, size_t ws_size,
                              hipStream_t stream) {
    const float* inp = (const float*)d_in[0];
    const float* T   = (const float*)d_in[1];
    float* out = (float*)d_out;
    float* Mws = (float*)d_ws;   // 256*2048 f32 = 2 MB

    hipMemsetAsync(Mws, 0, (size_t)NS * NOUT * sizeof(float), stream);
    mbd_copy_kernel<<<2048, 256, 0, stream>>>(inp, out);
    mbd_gemm_kernel<<<256, 256, 0, stream>>>(inp, T, Mws);
    mbd_pair_kernel<<<BD, 256, 0, stream>>>(Mws, out);
}

// Round 3
// 62.591 us; speedup vs baseline: 1.7904x; 1.7904x over previous
//
#include <hip/hip_runtime.h>
#include <hip/hip_bf16.h>

#define NS     256
#define FEAT   8192
#define BD     128
#define CD     16
#define NOUT   2048
#define OUTW   8320          // FEAT + BD
#define KSPLIT 16
#define KC     (FEAT / KSPLIT)   // 512
#define BK     32
#define NSTEP  (KC / BK)         // 16
#define LP     40                // LDS pitch in bf16 (80 B)

typedef float f32x4 __attribute__((ext_vector_type(4)));
typedef short bf16x8 __attribute__((ext_vector_type(8)));
typedef short bf16x4 __attribute__((ext_vector_type(4)));

__device__ __forceinline__ bf16x4 cvt4(float a, float b, float c, float d) {
    union { __hip_bfloat162 h[2]; bf16x4 s; } u;
    u.h[0] = __float22bfloat162_rn(float2{a, b});
    u.h[1] = __float22bfloat162_rn(float2{c, d});
    return u.s;
}

// ------------------------------------------------ copy inp + zero o-columns -
__global__ __launch_bounds__(256) void mbd_copy_kernel(const float* __restrict__ in,
                                                       float* __restrict__ out) {
    int row = blockIdx.y;
    int c4  = blockIdx.x * 256 + threadIdx.x;   // f32x4 index within out row
    if (c4 < 2048) {
        *(f32x4*)(out + (size_t)row * OUTW + c4 * 4) =
            *(const f32x4*)(in + (size_t)row * FEAT + c4 * 4);
    } else if (c4 < 2080) {
        *(f32x4*)(out + (size_t)row * OUTW + c4 * 4) = (f32x4){0.f, 0.f, 0.f, 0.f};
    }
}

// ---------------------------------------------------------------- GEMM ------
// Mt_part[kc][col][row] = (inp[:, kc-slice] @ T[kc-slice, :])^T, bf16 MFMA.
// A LDS [m][k] pitch 40; B LDS [n][k] pitch 40 (k-contiguous global loads).
// All loads compiler-generated (no inline asm) -> waitcnts correct.
template<bool SPLIT>
__global__ __launch_bounds__(256, 2) void mbd_gemm_kernel(const float* __restrict__ A,
                                                          const float* __restrict__ B,
                                                          float* __restrict__ C) {
    __shared__ short Als[2][128 * LP];   // 2 x 10240 B
    __shared__ short Bls[2][128 * LP];   // 2 x 10240 B

    const int tid = threadIdx.x, lane = tid & 63, l15 = lane & 15, w = tid >> 6;
    const int wr = (w >> 1) * 64, wc = (w & 1) * 64;

    // bijective XCD grouping: XCD x gets kc in {2x,2x+1}, all 32 tiles
    const int lg = (blockIdx.x & 7) * 64 + (blockIdx.x >> 3);
    const int kc = lg >> 5, tt = lg & 31;
    const int m0 = (tt & 1) * 128, n0 = (tt >> 1) * 128;
    const int kbase = kc * KC;

    // A staging: unit id -> (row, kquad), f32x4 loads
    const float* agp[4]; int awo[4];
#pragma unroll
    for (int i = 0; i < 4; ++i) {
        int id = tid + i * 256, row = id >> 3, kk = (id & 7) * 4;
        agp[i] = A + (size_t)(m0 + row) * FEAT + kbase + kk;
        awo[i] = row * LP + kk;
    }
    // B staging: lane owns column bn, k-quads q0,q0+2,q0+4,q0+6 (scalar loads,
    // each coalesced across the wave's 64 consecutive n)
    const int bn = tid & 127, q0 = tid >> 7;
    const float* bgp = B + (size_t)(kbase + q0 * 4) * NOUT + n0 + bn;
    int bwo[4];
#pragma unroll
    for (int i = 0; i < 4; ++i) bwo[i] = bn * LP + (q0 + 2 * i) * 4;

    const int kof = (lane >> 4) * 8;
    int aro[4], bro[4];
#pragma unroll
    for (int m = 0; m < 4; ++m) aro[m] = (wr + m * 16 + l15) * LP + kof;
#pragma unroll
    for (int n = 0; n < 4; ++n) bro[n] = (wc + n * 16 + l15) * LP + kof;

    f32x4 acc[4][4];
#pragma unroll
    for (int m = 0; m < 4; ++m)
#pragma unroll
        for (int n = 0; n < 4; ++n) acc[m][n] = (f32x4){0.f, 0.f, 0.f, 0.f};

    // prologue: stage tile 0
    f32x4 sa[4]; float sb[16];
#pragma unroll
    for (int i = 0; i < 4; ++i) sa[i] = *(const f32x4*)agp[i];
#pragma unroll
    for (int i = 0; i < 4; ++i)
#pragma unroll
        for (int j = 0; j < 4; ++j) sb[i * 4 + j] = bgp[(size_t)(8 * i + j) * NOUT];
#pragma unroll
    for (int i = 0; i < 4; ++i)
        *(bf16x4*)&Als[0][awo[i]] = cvt4(sa[i].x, sa[i].y, sa[i].z, sa[i].w);
#pragma unroll
    for (int i = 0; i < 4; ++i)
        *(bf16x4*)&Bls[0][bwo[i]] = cvt4(sb[i*4], sb[i*4+1], sb[i*4+2], sb[i*4+3]);
    __syncthreads();

    for (int kt = 0; kt < NSTEP; ++kt) {
        const int cur = kt & 1;
        if (kt + 1 < NSTEP) {   // issue next tile's loads early, hide under MFMA
#pragma unroll
            for (int i = 0; i < 4; ++i) sa[i] = *(const f32x4*)(agp[i] + (kt + 1) * BK);
            const float* bp = bgp + (size_t)(kt + 1) * BK * NOUT;
#pragma unroll
            for (int i = 0; i < 4; ++i)
#pragma unroll
                for (int j = 0; j < 4; ++j) sb[i * 4 + j] = bp[(size_t)(8 * i + j) * NOUT];
        }
        bf16x8 af[4], bf[4];
#pragma unroll
        for (int m = 0; m < 4; ++m) af[m] = *(const bf16x8*)&Als[cur][aro[m]];
#pragma unroll
        for (int n = 0; n < 4; ++n) bf[n] = *(const bf16x8*)&Bls[cur][bro[n]];
#pragma unroll
        for (int m = 0; m < 4; ++m)
#pragma unroll
            for (int n = 0; n < 4; ++n)
                acc[m][n] = __builtin_amdgcn_mfma_f32_16x16x32_bf16(
                    af[m], bf[n], acc[m][n], 0, 0, 0);
        if (kt + 1 < NSTEP) {   // convert + write next buffer, single barrier
#pragma unroll
            for (int i = 0; i < 4; ++i)
                *(bf16x4*)&Als[cur ^ 1][awo[i]] = cvt4(sa[i].x, sa[i].y, sa[i].z, sa[i].w);
#pragma unroll
            for (int i = 0; i < 4; ++i)
                *(bf16x4*)&Bls[cur ^ 1][bwo[i]] =
                    cvt4(sb[i*4], sb[i*4+1], sb[i*4+2], sb[i*4+3]);
            __syncthreads();
        }
    }

    // epilogue: C/D layout col = l&15, row = (l>>4)*4 + r  [m89-verified]
    // -> acc[m][n] is 4 consecutive rows at one col: f32x4 store into Mt[col][row]
    float* Cp = SPLIT ? (C + (size_t)kc * NOUT * NS) : C;
    const int r0 = (lane >> 4) * 4;
#pragma unroll
    for (int m = 0; m < 4; ++m)
#pragma unroll
        for (int n = 0; n < 4; ++n) {
            int col = n0 + wc + n * 16 + l15;
            int row = m0 + wr + m * 16 + r0;
            if (SPLIT) {
                *(f32x4*)&Cp[(size_t)col * NS + row] = acc[m][n];
            } else {
#pragma unroll
                for (int r = 0; r < 4; ++r)
                    atomicAdd(&Cp[(size_t)col * NS + row + r], acc[m][n][r]);
            }
        }
}

// ---------------------------------------------------------------- pairwise --
// block (b, jhalf): o_part[i,b] = sum_{j in half} exp(-sum_c |M[i,c]-M[j,c]|)
// Mt layout [p][col][row]; partial-fold reads fully coalesced.
template<int NPARTS>
__global__ __launch_bounds__(256) void mbd_pair_kernel(const float* __restrict__ Mt,
                                                       float* __restrict__ out) {
    const int b = blockIdx.x >> 1, jh = blockIdx.x & 1;
    const int t = threadIdx.x;
    __shared__ float ldsT[CD][NS];       // [c][row] 16 KB
    __shared__ float rows[NS][20];       // [row][c] padded (80 B pitch) 20 KB

#pragma unroll
    for (int u4 = 0; u4 < 4; ++u4) {
        int u = t + u4 * 256;
        int c = u >> 6, r4 = (u & 63) * 4;
        f32x4 v = (f32x4){0.f, 0.f, 0.f, 0.f};
#pragma unroll
        for (int p = 0; p < NPARTS; ++p)
            v += *(const f32x4*)(Mt + ((size_t)p * NOUT + (size_t)b * CD + c) * NS + r4);
        *(f32x4*)&ldsT[c][r4] = v;
    }
    __syncthreads();

    float my[16];
#pragma unroll
    for (int c = 0; c < 16; ++c) my[c] = ldsT[c][t];   // contiguous -> conflict-free
#pragma unroll
    for (int c = 0; c < 16; ++c) rows[t][c] = my[c];
    __syncthreads();

    float o0 = 0.f, o1 = 0.f;
    const int jbase = jh * 128;
    for (int jj = 0; jj < 128; jj += 2) {
#pragma unroll
        for (int s = 0; s < 2; ++s) {
            const float* rp = &rows[jbase + jj + s][0];   // uniform -> broadcast
            float d0 = 0.f, d1 = 0.f, d2 = 0.f, d3 = 0.f;
#pragma unroll
            for (int q = 0; q < 4; ++q) {
                f32x4 r = *(const f32x4*)(rp + q * 4);
                d0 += fabsf(my[q * 4 + 0] - r.x);
                d1 += fabsf(my[q * 4 + 1] - r.y);
                d2 += fabsf(my[q * 4 + 2] - r.z);
                d3 += fabsf(my[q * 4 + 3] - r.w);
            }
            float d = (d0 + d1) + (d2 + d3);
            if (s == 0) o0 += __expf(-d); else o1 += __expf(-d);
        }
    }
    // exactly two addends per address -> f32 add commutative -> deterministic
    atomicAdd(&out[(size_t)t * OUTW + FEAT + b], o0 + o1);
}

// ---------------------------------------------------------------- launch ----
extern "C" void kernel_launch(void* const* d_in, const int* in_sizes, int n_in,
                              void* d_out, int out_size, void* d_ws, size_t ws_size,
                              hipStream_t stream) {
    const float* inp = (const float*)d_in[0];
    const float* T   = (const float*)d_in[1];
    float* out = (float*)d_out;
    float* ws  = (float*)d_ws;

    const size_t needSplit = (size_t)KSPLIT * NOUT * NS * sizeof(float);  // 32 MiB

    mbd_copy_kernel<<<dim3(9, 256), 256, 0, stream>>>(inp, out);  // also zeroes o-cols
    if (ws_size >= needSplit) {
        mbd_gemm_kernel<true><<<512, 256, 0, stream>>>(inp, T, ws);
        mbd_pair_kernel<KSPLIT><<<BD * 2, 256, 0, stream>>>(ws, out);
    } else {
        hipMemsetAsync(ws, 0, (size_t)NOUT * NS * sizeof(float), stream);
        mbd_gemm_kernel<false><<<512, 256, 0, stream>>>(inp, T, ws);
        mbd_pair_kernel<1><<<BD * 2, 256, 0, stream>>>(ws, out);
    }
}

// Round 4
// 60.493 us; speedup vs baseline: 1.8525x; 1.0347x over previous
//
#include <hip/hip_runtime.h>
#include <hip/hip_bf16.h>

#define NS     256
#define FEAT   8192
#define BD     128
#define CD     16
#define NOUT   2048
#define OUTW   8320          // FEAT + BD
#define KSPLIT 16
#define KC     (FEAT / KSPLIT)   // 512
#define BK     32
#define NSTEP  (KC / BK)         // 16
#define LP     40                // LDS pitch in bf16 (80 B)

typedef float f32x4 __attribute__((ext_vector_type(4)));
typedef short bf16x8 __attribute__((ext_vector_type(8)));
typedef short bf16x4 __attribute__((ext_vector_type(4)));

__device__ __forceinline__ bf16x4 cvt4(float a, float b, float c, float d) {
    union { __hip_bfloat162 h[2]; bf16x4 s; } u;
    u.h[0] = __float22bfloat162_rn(float2{a, b});
    u.h[1] = __float22bfloat162_rn(float2{c, d});
    return u.s;
}

// ------------------------------------------------ copy inp + zero o-columns -
__global__ __launch_bounds__(256) void mbd_copy_kernel(const float* __restrict__ in,
                                                       float* __restrict__ out) {
    int row = blockIdx.y;
    int c4  = blockIdx.x * 256 + threadIdx.x;   // f32x4 index within out row
    if (c4 < 2048) {
        *(f32x4*)(out + (size_t)row * OUTW + c4 * 4) =
            *(const f32x4*)(in + (size_t)row * FEAT + c4 * 4);
    } else if (c4 < 2080) {
        *(f32x4*)(out + (size_t)row * OUTW + c4 * 4) = (f32x4){0.f, 0.f, 0.f, 0.f};
    }
}

// ---------------------------------------------------------------- GEMM ------
// Mt_part[kc][col][row] = (inp[:, kc-slice] @ T[kc-slice, :])^T, bf16 MFMA.
// A LDS [m][k] pitch 40; B LDS [n][k] pitch 40 (k-contiguous global loads).
// Phase order pinned with sched_barrier(0): loads | ds_read+MFMA | cvt+ds_write.
template<bool SPLIT>
__global__ __launch_bounds__(256, 2) void mbd_gemm_kernel(const float* __restrict__ A,
                                                          const float* __restrict__ B,
                                                          float* __restrict__ C) {
    __shared__ short Als[2][128 * LP];   // 2 x 10240 B
    __shared__ short Bls[2][128 * LP];   // 2 x 10240 B

    const int tid = threadIdx.x, lane = tid & 63, l15 = lane & 15, w = tid >> 6;
    const int wr = (w >> 1) * 64, wc = (w & 1) * 64;

    // bijective XCD grouping: XCD x gets kc in {2x,2x+1}, all 32 tiles
    const int lg = (blockIdx.x & 7) * 64 + (blockIdx.x >> 3);
    const int kc = lg >> 5, tt = lg & 31;
    const int m0 = (tt & 1) * 128, n0 = (tt >> 1) * 128;
    const int kbase = kc * KC;

    // A staging: unit id -> (row, kquad), f32x4 loads
    const float* agp[4]; int awo[4];
#pragma unroll
    for (int i = 0; i < 4; ++i) {
        int id = tid + i * 256, row = id >> 3, kk = (id & 7) * 4;
        agp[i] = A + (size_t)(m0 + row) * FEAT + kbase + kk;
        awo[i] = row * LP + kk;
    }
    // B staging: lane owns column bn, 16 k's (scalar loads, each wave-coalesced)
    const int bn = tid & 127, q0 = tid >> 7;
    const float* bgp = B + (size_t)(kbase + q0 * 4) * NOUT + n0 + bn;
    int bwo[4];
#pragma unroll
    for (int i = 0; i < 4; ++i) bwo[i] = bn * LP + (q0 + 2 * i) * 4;

    const int kof = (lane >> 4) * 8;
    int aro[4], bro[4];
#pragma unroll
    for (int m = 0; m < 4; ++m) aro[m] = (wr + m * 16 + l15) * LP + kof;
#pragma unroll
    for (int n = 0; n < 4; ++n) bro[n] = (wc + n * 16 + l15) * LP + kof;

    f32x4 acc[4][4];
#pragma unroll
    for (int m = 0; m < 4; ++m)
#pragma unroll
        for (int n = 0; n < 4; ++n) acc[m][n] = (f32x4){0.f, 0.f, 0.f, 0.f};

    // prologue: stage tile 0
    f32x4 sa[4]; float sb[16];
#pragma unroll
    for (int i = 0; i < 4; ++i) sa[i] = *(const f32x4*)agp[i];
#pragma unroll
    for (int i = 0; i < 4; ++i)
#pragma unroll
        for (int j = 0; j < 4; ++j) sb[i * 4 + j] = bgp[(size_t)(8 * i + j) * NOUT];
#pragma unroll
    for (int i = 0; i < 4; ++i)
        *(bf16x4*)&Als[0][awo[i]] = cvt4(sa[i].x, sa[i].y, sa[i].z, sa[i].w);
#pragma unroll
    for (int i = 0; i < 4; ++i)
        *(bf16x4*)&Bls[0][bwo[i]] = cvt4(sb[i*4], sb[i*4+1], sb[i*4+2], sb[i*4+3]);
    __syncthreads();

    for (int kt = 0; kt < NSTEP; ++kt) {
        const int cur = kt & 1;
        // ---- phase 1: issue next tile's global loads (longest latency first)
        if (kt + 1 < NSTEP) {
#pragma unroll
            for (int i = 0; i < 4; ++i) sa[i] = *(const f32x4*)(agp[i] + (kt + 1) * BK);
            const float* bp = bgp + (size_t)(kt + 1) * BK * NOUT;
#pragma unroll
            for (int i = 0; i < 4; ++i)
#pragma unroll
                for (int j = 0; j < 4; ++j) sb[i * 4 + j] = bp[(size_t)(8 * i + j) * NOUT];
        }
        __builtin_amdgcn_sched_barrier(0);   // loads stay above; no vmcnt wait below yet
        // ---- phase 2: LDS fragments + MFMA (depends only on lgkmcnt)
        bf16x8 af[4], bf[4];
#pragma unroll
        for (int m = 0; m < 4; ++m) af[m] = *(const bf16x8*)&Als[cur][aro[m]];
#pragma unroll
        for (int n = 0; n < 4; ++n) bf[n] = *(const bf16x8*)&Bls[cur][bro[n]];
        __builtin_amdgcn_s_setprio(1);
#pragma unroll
        for (int m = 0; m < 4; ++m)
#pragma unroll
            for (int n = 0; n < 4; ++n)
                acc[m][n] = __builtin_amdgcn_mfma_f32_16x16x32_bf16(
                    af[m], bf[n], acc[m][n], 0, 0, 0);
        __builtin_amdgcn_s_setprio(0);
        __builtin_amdgcn_sched_barrier(0);   // cvt/ds_write (and its vmcnt) stay below
        // ---- phase 3: wait loads, convert, write next buffer, barrier
        if (kt + 1 < NSTEP) {
#pragma unroll
            for (int i = 0; i < 4; ++i)
                *(bf16x4*)&Als[cur ^ 1][awo[i]] = cvt4(sa[i].x, sa[i].y, sa[i].z, sa[i].w);
#pragma unroll
            for (int i = 0; i < 4; ++i)
                *(bf16x4*)&Bls[cur ^ 1][bwo[i]] =
                    cvt4(sb[i*4], sb[i*4+1], sb[i*4+2], sb[i*4+3]);
            __syncthreads();
        }
    }

    // epilogue: C/D layout col = l&15, row = (l>>4)*4 + r  [m89-verified]
    // -> acc[m][n] is 4 consecutive rows at one col: f32x4 store into Mt[col][row]
    float* Cp = SPLIT ? (C + (size_t)kc * NOUT * NS) : C;
    const int r0 = (lane >> 4) * 4;
#pragma unroll
    for (int m = 0; m < 4; ++m)
#pragma unroll
        for (int n = 0; n < 4; ++n) {
            int col = n0 + wc + n * 16 + l15;
            int row = m0 + wr + m * 16 + r0;
            if (SPLIT) {
                *(f32x4*)&Cp[(size_t)col * NS + row] = acc[m][n];
            } else {
#pragma unroll
                for (int r = 0; r < 4; ++r)
                    atomicAdd(&Cp[(size_t)col * NS + row + r], acc[m][n][r]);
            }
        }
}

// ---------------------------------------------------------------- pairwise --
// block (b, jhalf): o_part[i,b] = sum_{j in half} exp(-sum_c |M[i,c]-M[j,c]|)
// Mt layout [p][col][row]; partial-fold reads fully coalesced.
template<int NPARTS>
__global__ __launch_bounds__(256) void mbd_pair_kernel(const float* __restrict__ Mt,
                                                       float* __restrict__ out) {
    const int b = blockIdx.x >> 1, jh = blockIdx.x & 1;
    const int t = threadIdx.x;
    __shared__ float ldsT[CD][NS];       // [c][row] 16 KB
    __shared__ float rows[NS][20];       // [row][c] padded (80 B pitch) 20 KB

#pragma unroll
    for (int u4 = 0; u4 < 4; ++u4) {
        int u = t + u4 * 256;
        int c = u >> 6, r4 = (u & 63) * 4;
        f32x4 v = (f32x4){0.f, 0.f, 0.f, 0.f};
#pragma unroll
        for (int p = 0; p < NPARTS; ++p)
            v += *(const f32x4*)(Mt + ((size_t)p * NOUT + (size_t)b * CD + c) * NS + r4);
        *(f32x4*)&ldsT[c][r4] = v;
    }
    __syncthreads();

    float my[16];
#pragma unroll
    for (int c = 0; c < 16; ++c) my[c] = ldsT[c][t];   // contiguous -> conflict-free
#pragma unroll
    for (int c = 0; c < 16; ++c) rows[t][c] = my[c];
    __syncthreads();

    float o0 = 0.f, o1 = 0.f;
    const int jbase = jh * 128;
    for (int jj = 0; jj < 128; jj += 2) {
#pragma unroll
        for (int s = 0; s < 2; ++s) {
            const float* rp = &rows[jbase + jj + s][0];   // uniform -> broadcast
            float d0 = 0.f, d1 = 0.f, d2 = 0.f, d3 = 0.f;
#pragma unroll
            for (int q = 0; q < 4; ++q) {
                f32x4 r = *(const f32x4*)(rp + q * 4);
                d0 += fabsf(my[q * 4 + 0] - r.x);
                d1 += fabsf(my[q * 4 + 1] - r.y);
                d2 += fabsf(my[q * 4 + 2] - r.z);
                d3 += fabsf(my[q * 4 + 3] - r.w);
            }
            float d = (d0 + d1) + (d2 + d3);
            if (s == 0) o0 += __expf(-d); else o1 += __expf(-d);
        }
    }
    // exactly two addends per address -> f32 add commutative -> deterministic
    atomicAdd(&out[(size_t)t * OUTW + FEAT + b], o0 + o1);
}

// ---------------------------------------------------------------- launch ----
extern "C" void kernel_launch(void* const* d_in, const int* in_sizes, int n_in,
                              void* d_out, int out_size, void* d_ws, size_t ws_size,
                              hipStream_t stream) {
    const float* inp = (const float*)d_in[0];
    const float* T   = (const float*)d_in[1];
    float* out = (float*)d_out;
    float* ws  = (float*)d_ws;

    const size_t needSplit = (size_t)KSPLIT * NOUT * NS * sizeof(float);  // 32 MiB

    mbd_copy_kernel<<<dim3(9, 256), 256, 0, stream>>>(inp, out);  // also zeroes o-cols
    if (ws_size >= needSplit) {
        mbd_gemm_kernel<true><<<512, 256, 0, stream>>>(inp, T, ws);
        mbd_pair_kernel<KSPLIT><<<BD * 2, 256, 0, stream>>>(ws, out);
    } else {
        hipMemsetAsync(ws, 0, (size_t)NOUT * NS * sizeof(float), stream);
        mbd_gemm_kernel<false><<<512, 256, 0, stream>>>(inp, T, ws);
        mbd_pair_kernel<1><<<BD * 2, 256, 0, stream>>>(ws, out);
    }
}